// Round 1
// baseline (3772.512 us; speedup 1.0000x reference)
//
#include <hip/hip_runtime.h>
#include <math.h>

// Problem constants
#define Tn 30
#define Bn 16384
#define Hn 100
#define G4 400     // 4*H
#define Pn 7
#define ROWS 64    // batch rows per block
#define PITCH 101  // LDS row pitch (101 % 32 = 5, coprime -> 2-way bank access, free)
#define NTHREADS 512   // 8 waves; wave w handles hidden-chunk q=w

__device__ __forceinline__ float sigmoidf_(float v) {
    return 1.0f / (1.0f + __expf(-v));
}
__device__ __forceinline__ float tanhf_(float v) {
    // stable: large +v -> 1, large -v -> -1
    return 1.0f - 2.0f / (__expf(2.0f * v) + 1.0f);
}

// ws[0..399]   = u1[j]  = sum_k Wih1[j,k] * W1[k]        (rank-1 fold of FC1)
// ws[400..799] = wc1[j] = sum_k Wih1[j,k] * b1[k] + bih1[j] + bhh1[j]
__global__ void precompute_kernel(const float* __restrict__ W1,
                                  const float* __restrict__ b1,
                                  const float* __restrict__ Wih1,
                                  const float* __restrict__ bih1,
                                  const float* __restrict__ bhh1,
                                  float* __restrict__ ws) {
    int j = blockIdx.x * blockDim.x + threadIdx.x;
    if (j < G4) {
        float u = 0.f, w = 0.f;
        for (int k = 0; k < Hn; ++k) {
            float a = Wih1[j * Hn + k];
            u += a * W1[k];
            w += a * b1[k];
        }
        ws[j] = u;
        ws[G4 + j] = w + bih1[j] + bhh1[j];
    }
}

// One r-tile of LSTM1 gates: g = x*u1 + wc1 + h . Whh1^T, then activations + c/h update.
template <int NE>
__device__ __forceinline__ void step_tile_1(const float* __restrict__ whh,
                                            const float* __restrict__ hrow,  // LDS &h[row][0]
                                            const float* __restrict__ u1,
                                            const float* __restrict__ wc1,
                                            float xv, int j0,
                                            float* __restrict__ cloc,
                                            float* __restrict__ hloc) {
    float acc[4][NE];
#pragma unroll
    for (int g = 0; g < 4; ++g)
#pragma unroll
        for (int e = 0; e < NE; ++e) {
            int j = g * Hn + j0 + e;
            acc[g][e] = xv * u1[j] + wc1[j];
        }
#pragma unroll 2
    for (int k = 0; k < Hn; ++k) {
        float a = hrow[k];
#pragma unroll
        for (int g = 0; g < 4; ++g)
#pragma unroll
            for (int e = 0; e < NE; ++e)
                acc[g][e] += a * whh[(g * Hn + j0 + e) * Hn + k];
    }
#pragma unroll
    for (int e = 0; e < NE; ++e) {
        float iv = sigmoidf_(acc[0][e]);
        float fv = sigmoidf_(acc[1][e]);
        float gv = tanhf_(acc[2][e]);
        float ov = sigmoidf_(acc[3][e]);
        float cc = fv * cloc[e] + iv * gv;
        cloc[e] = cc;
        hloc[e] = ov * tanhf_(cc);
    }
}

// One r-tile of LSTM2 gates: g = (bih2+bhh2) + last . Wih2^T + h2 . Whh2^T,
// activations + c/h update, and incremental FC2 accumulation into yacc[7].
template <int NE>
__device__ __forceinline__ void step_tile_2(const float* __restrict__ whh2,
                                            const float* __restrict__ hrow,   // LDS h2
                                            const float* __restrict__ wih2,
                                            const float* __restrict__ lrow,   // LDS last
                                            const float* __restrict__ bih2,
                                            const float* __restrict__ bhh2,
                                            const float* __restrict__ w2,
                                            int ps, int j0,
                                            float* __restrict__ cloc,
                                            float* __restrict__ hloc,
                                            float* __restrict__ yacc) {
    float acc[4][NE];
#pragma unroll
    for (int g = 0; g < 4; ++g)
#pragma unroll
        for (int e = 0; e < NE; ++e) {
            int j = g * Hn + j0 + e;
            acc[g][e] = bih2[j] + bhh2[j];
        }
#pragma unroll 2
    for (int k = 0; k < Hn; ++k) {
        float a = hrow[k];
        float l = lrow[k];
#pragma unroll
        for (int g = 0; g < 4; ++g)
#pragma unroll
            for (int e = 0; e < NE; ++e) {
                int r = (g * Hn + j0 + e) * Hn + k;
                acc[g][e] += a * whh2[r];
                acc[g][e] += l * wih2[r];
            }
    }
#pragma unroll
    for (int e = 0; e < NE; ++e) {
        float iv = sigmoidf_(acc[0][e]);
        float fv = sigmoidf_(acc[1][e]);
        float gv = tanhf_(acc[2][e]);
        float ov = sigmoidf_(acc[3][e]);
        float cc = fv * cloc[e] + iv * gv;
        cloc[e] = cc;
        float hv = ov * tanhf_(cc);
        hloc[e] = hv;
#pragma unroll
        for (int p = 0; p < Pn; ++p)
            yacc[p] += w2[p * (Pn * Hn) + ps * Hn + j0 + e] * hv;
    }
}

__global__ __launch_bounds__(NTHREADS) void lstm_fused(
    const float* __restrict__ x,     // (T,B)
    const float* __restrict__ whh1,  // (400,100)
    const float* __restrict__ wih2,  // (400,100)
    const float* __restrict__ whh2,  // (400,100)
    const float* __restrict__ bih2,
    const float* __restrict__ bhh2,
    const float* __restrict__ w2,    // (7,700)
    const float* __restrict__ b2,    // (7,)
    const float* __restrict__ uc,    // ws: u1[400], wc1[400]
    float* __restrict__ out)         // (B,7)
{
    __shared__ float smem[2 * ROWS * PITCH];
    float* h_s = smem;                     // h (LSTM1), then h2 (LSTM2)
    float* last_s = smem + ROWS * PITCH;   // h after step 30 (constant LSTM2 input)
    float* ypart = smem;                   // aliases h_s; used only after last h read

    const int tid = threadIdx.x;
    const int row = tid & 63;
    // q is wave-uniform by construction (64-aligned waves); force SGPR so Whh/W2/u1
    // addressing is provably uniform -> scalar-cache loads.
    const int q = __builtin_amdgcn_readfirstlane(tid) >> 6;  // 0..7
    const int rstart = (q < 4) ? 13 * q : 52 + 12 * (q - 4);
    const int big = (q < 4);  // 13 r's, else 12
    const int b = blockIdx.x * ROWS + row;

    float c[13], hnew[13], yacc[Pn];
#pragma unroll
    for (int i = 0; i < 13; ++i) c[i] = 0.f;
#pragma unroll
    for (int p = 0; p < Pn; ++p) yacc[p] = 0.f;

    for (int i = tid; i < ROWS * PITCH; i += NTHREADS) h_s[i] = 0.f;
    __syncthreads();

    const float* u1 = uc;
    const float* wc1 = uc + G4;
    const float* hrow = h_s + row * PITCH;
    const float* lrow = last_s + row * PITCH;

    // ---- LSTM1: 30 steps ----
    for (int t = 0; t < Tn; ++t) {
        float xv = x[t * Bn + b];
        if (big) {
            step_tile_1<5>(whh1, hrow, u1, wc1, xv, rstart + 0, &c[0], &hnew[0]);
            step_tile_1<4>(whh1, hrow, u1, wc1, xv, rstart + 5, &c[5], &hnew[5]);
            step_tile_1<4>(whh1, hrow, u1, wc1, xv, rstart + 9, &c[9], &hnew[9]);
        } else {
            step_tile_1<4>(whh1, hrow, u1, wc1, xv, rstart + 0, &c[0], &hnew[0]);
            step_tile_1<4>(whh1, hrow, u1, wc1, xv, rstart + 4, &c[4], &hnew[4]);
            step_tile_1<4>(whh1, hrow, u1, wc1, xv, rstart + 8, &c[8], &hnew[8]);
        }
        __syncthreads();  // all reads of old h done
        {
            const int n = big ? 13 : 12;
            for (int e = 0; e < n; ++e) {
                h_s[row * PITCH + rstart + e] = hnew[e];
                if (t == Tn - 1) last_s[row * PITCH + rstart + e] = hnew[e];
            }
        }
        __syncthreads();  // new h visible
    }

    // ---- LSTM2: 7 steps, input = last (constant), carry continues ----
    for (int ps = 0; ps < Pn; ++ps) {
        if (big) {
            step_tile_2<5>(whh2, hrow, wih2, lrow, bih2, bhh2, w2, ps, rstart + 0, &c[0], &hnew[0], yacc);
            step_tile_2<4>(whh2, hrow, wih2, lrow, bih2, bhh2, w2, ps, rstart + 5, &c[5], &hnew[5], yacc);
            step_tile_2<4>(whh2, hrow, wih2, lrow, bih2, bhh2, w2, ps, rstart + 9, &c[9], &hnew[9], yacc);
        } else {
            step_tile_2<4>(whh2, hrow, wih2, lrow, bih2, bhh2, w2, ps, rstart + 0, &c[0], &hnew[0], yacc);
            step_tile_2<4>(whh2, hrow, wih2, lrow, bih2, bhh2, w2, ps, rstart + 4, &c[4], &hnew[4], yacc);
            step_tile_2<4>(whh2, hrow, wih2, lrow, bih2, bhh2, w2, ps, rstart + 8, &c[8], &hnew[8], yacc);
        }
        __syncthreads();  // all reads of h2/last done
        if (ps < Pn - 1) {
            const int n = big ? 13 : 12;
            for (int e = 0; e < n; ++e)
                h_s[row * PITCH + rstart + e] = hnew[e];
        }
        __syncthreads();
    }

    // ---- FC2 reduce across the 8 hidden-chunks + bias + sigmoid ----
    // (ypart aliases h_s: safe, last h_s read was before the final barrier)
#pragma unroll
    for (int p = 0; p < Pn; ++p)
        ypart[(q * ROWS + row) * Pn + p] = yacc[p];
    __syncthreads();
    if (tid < ROWS) {
        int bb = blockIdx.x * ROWS + tid;
#pragma unroll
        for (int p = 0; p < Pn; ++p) {
            float s = b2[p];
#pragma unroll
            for (int qq = 0; qq < 8; ++qq)
                s += ypart[(qq * ROWS + tid) * Pn + p];
            out[bb * Pn + p] = sigmoidf_(s);
        }
    }
}

extern "C" void kernel_launch(void* const* d_in, const int* in_sizes, int n_in,
                              void* d_out, int out_size, void* d_ws, size_t ws_size,
                              hipStream_t stream) {
    const float* x    = (const float*)d_in[0];
    const float* W1   = (const float*)d_in[1];
    const float* b1   = (const float*)d_in[2];
    const float* Wih1 = (const float*)d_in[3];
    const float* Whh1 = (const float*)d_in[4];
    const float* bih1 = (const float*)d_in[5];
    const float* bhh1 = (const float*)d_in[6];
    const float* Wih2 = (const float*)d_in[7];
    const float* Whh2 = (const float*)d_in[8];
    const float* bih2 = (const float*)d_in[9];
    const float* bhh2 = (const float*)d_in[10];
    const float* W2   = (const float*)d_in[11];
    const float* b2   = (const float*)d_in[12];
    float* out = (float*)d_out;
    float* ws  = (float*)d_ws;

    precompute_kernel<<<2, 256, 0, stream>>>(W1, b1, Wih1, bih1, bhh1, ws);
    lstm_fused<<<Bn / ROWS, NTHREADS, 0, stream>>>(x, Whh1, Wih2, Whh2, bih2, bhh2,
                                                   W2, b2, ws, out);
}

// Round 2
// 2991.587 us; speedup vs baseline: 1.2610x; 1.2610x over previous
//
#include <hip/hip_runtime.h>
#include <math.h>

// Problem constants
#define Tn 30
#define Bn 16384
#define Hn 100
#define G4 400      // 4*H
#define Pn 7
#define ROWS 32     // batch rows per block
#define KC 25       // k-chunks of 4 (Hn/4)
#define NTHREADS 640  // 10 waves; 20 half-wave chunks of NU=5 hidden units
#define NU 5          // hidden units per thread (x4 gates = 20 accumulators)
#define NBLK (Bn / ROWS)   // 512 blocks -> 2 blocks/CU

__device__ __forceinline__ float sigmoidf_(float v) {
    return 1.0f / (1.0f + __expf(-v));
}
__device__ __forceinline__ float tanhf_(float v) {
    return 1.0f - 2.0f / (__expf(2.0f * v) + 1.0f);
}

// ws[0..399]   = u1[j]  = sum_k Wih1[j,k] * W1[k]      (rank-1 fold of FC1)
// ws[400..799] = wc1[j] = sum_k Wih1[j,k] * b1[k] + bih1[j] + bhh1[j]
__global__ void precompute_kernel(const float* __restrict__ W1,
                                  const float* __restrict__ b1,
                                  const float* __restrict__ Wih1,
                                  const float* __restrict__ bih1,
                                  const float* __restrict__ bhh1,
                                  float* __restrict__ ws) {
    int j = blockIdx.x * blockDim.x + threadIdx.x;
    if (j < G4) {
        float u = 0.f, w = 0.f;
        for (int k = 0; k < Hn; ++k) {
            float a = Wih1[j * Hn + k];
            u += a * W1[k];
            w += a * b1[k];
        }
        ws[j] = u;
        ws[G4 + j] = w + bih1[j] + bhh1[j];
    }
}

// Dot-accumulate 20 gate accumulators over k using vector (vmcnt) weight loads.
// hb layout: hbuf[kc][row][4] -> lane-contiguous 16B ds_read_b128, conflict-free.
__device__ __forceinline__ void dot_k(const float* __restrict__ w0,
                                      const float* __restrict__ w1,
                                      const float* __restrict__ w2g,
                                      const float* __restrict__ w3,
                                      const float* __restrict__ hb, int row,
                                      float acc[4][NU]) {
#pragma unroll 2
    for (int kc = 0; kc < KC; ++kc) {
        const float4 h4 = *(const float4*)(hb + (kc * ROWS + row) * 4);
#pragma unroll
        for (int e = 0; e < NU; ++e) {
            float4 a0 = *(const float4*)(w0 + e * Hn + kc * 4);
            float4 a1 = *(const float4*)(w1 + e * Hn + kc * 4);
            float4 a2 = *(const float4*)(w2g + e * Hn + kc * 4);
            float4 a3 = *(const float4*)(w3 + e * Hn + kc * 4);
            acc[0][e] = fmaf(h4.w, a0.w, fmaf(h4.z, a0.z, fmaf(h4.y, a0.y, fmaf(h4.x, a0.x, acc[0][e]))));
            acc[1][e] = fmaf(h4.w, a1.w, fmaf(h4.z, a1.z, fmaf(h4.y, a1.y, fmaf(h4.x, a1.x, acc[1][e]))));
            acc[2][e] = fmaf(h4.w, a2.w, fmaf(h4.z, a2.z, fmaf(h4.y, a2.y, fmaf(h4.x, a2.x, acc[2][e]))));
            acc[3][e] = fmaf(h4.w, a3.w, fmaf(h4.z, a3.z, fmaf(h4.y, a3.y, fmaf(h4.x, a3.x, acc[3][e]))));
        }
    }
}

__device__ __forceinline__ void gates_update(float acc[4][NU], float* __restrict__ c,
                                             float* __restrict__ hn) {
#pragma unroll
    for (int e = 0; e < NU; ++e) {
        float iv = sigmoidf_(acc[0][e]);
        float fv = sigmoidf_(acc[1][e]);
        float gv = tanhf_(acc[2][e]);
        float ov = sigmoidf_(acc[3][e]);
        float cc = fv * c[e] + iv * gv;
        c[e] = cc;
        hn[e] = ov * tanhf_(cc);
    }
}

__global__ __launch_bounds__(NTHREADS, 5) void lstm_fused(
    const float* __restrict__ x,     // (T,B)
    const float* __restrict__ whh1,  // (400,100)
    const float* __restrict__ wih2,  // (400,100)
    const float* __restrict__ whh2,  // (400,100)
    const float* __restrict__ bih2,  // (400,)
    const float* __restrict__ bhh2,  // (400,)
    const float* __restrict__ w2,    // (7,700)
    const float* __restrict__ b2,    // (7,)
    const float* __restrict__ uc,    // ws: u1[400], wc1[400]
    float* __restrict__ out)         // (B,7)
{
    __shared__ float hbuf[KC * ROWS * 4];   // h, k-chunk-major: [kc][row][4]
    __shared__ float g2s[G4 * ROWS];        // gin2[j][row]; later aliased as ypart

    const int tid = threadIdx.x;
    const int row = tid & 31;          // batch row within block
    const int hq = tid >> 5;           // half-wave chunk id, 0..19 (lane-derived: keeps
                                       // weight loads VECTOR (vmcnt), not s_load (lgkm))
    const int j0 = NU * hq;            // first hidden unit of this thread's chunk
    const int b = blockIdx.x * ROWS + row;

    float c[NU], hn[NU], yacc[Pn];
#pragma unroll
    for (int e = 0; e < NU; ++e) c[e] = 0.f;
#pragma unroll
    for (int p = 0; p < Pn; ++p) yacc[p] = 0.f;

    for (int i = tid; i < KC * ROWS * 4; i += NTHREADS) hbuf[i] = 0.f;
    __syncthreads();

    const float* u1 = uc;
    const float* wc1 = uc + G4;

    // per-gate weight row bases for this thread's chunk (e*Hn + kc*4 added inside)
    const float* a10 = whh1 + (0 * Hn + j0) * Hn;
    const float* a11 = whh1 + (1 * Hn + j0) * Hn;
    const float* a12 = whh1 + (2 * Hn + j0) * Hn;
    const float* a13 = whh1 + (3 * Hn + j0) * Hn;

    // ---- LSTM1: 30 steps ----
    for (int t = 0; t < Tn; ++t) {
        float xv = x[t * Bn + b];
        float acc[4][NU];
#pragma unroll
        for (int g = 0; g < 4; ++g)
#pragma unroll
            for (int e = 0; e < NU; ++e) {
                int j = g * Hn + j0 + e;
                acc[g][e] = fmaf(xv, u1[j], wc1[j]);
            }
        dot_k(a10, a11, a12, a13, hbuf, row, acc);
        gates_update(acc, c, hn);
        __syncthreads();   // all reads of old h done
#pragma unroll
        for (int e = 0; e < NU; ++e) {
            int j = j0 + e;
            hbuf[((j >> 2) * ROWS + row) * 4 + (j & 3)] = hn[e];
        }
        __syncthreads();   // new h visible
    }
    // hbuf now holds `last` (= h after step 30) == initial h2.

    // ---- gin2 = last @ Wih2^T + bih2 + bhh2  (constant across the 7 LSTM2 steps) ----
    {
        const float* b10 = wih2 + (0 * Hn + j0) * Hn;
        const float* b11 = wih2 + (1 * Hn + j0) * Hn;
        const float* b12 = wih2 + (2 * Hn + j0) * Hn;
        const float* b13 = wih2 + (3 * Hn + j0) * Hn;
        float acc[4][NU];
#pragma unroll
        for (int g = 0; g < 4; ++g)
#pragma unroll
            for (int e = 0; e < NU; ++e) {
                int j = g * Hn + j0 + e;
                acc[g][e] = bih2[j] + bhh2[j];
            }
        dot_k(b10, b11, b12, b13, hbuf, row, acc);
#pragma unroll
        for (int g = 0; g < 4; ++g)
#pragma unroll
            for (int e = 0; e < NU; ++e)
                g2s[(g * Hn + j0 + e) * ROWS + row] = acc[g][e];
    }
    __syncthreads();

    // ---- LSTM2: 7 steps (input projection folded into g2s) ----
    const float* c10 = whh2 + (0 * Hn + j0) * Hn;
    const float* c11 = whh2 + (1 * Hn + j0) * Hn;
    const float* c12 = whh2 + (2 * Hn + j0) * Hn;
    const float* c13 = whh2 + (3 * Hn + j0) * Hn;
    for (int ps = 0; ps < Pn; ++ps) {
        float acc[4][NU];
#pragma unroll
        for (int g = 0; g < 4; ++g)
#pragma unroll
            for (int e = 0; e < NU; ++e)
                acc[g][e] = g2s[(g * Hn + j0 + e) * ROWS + row];
        dot_k(c10, c11, c12, c13, hbuf, row, acc);
        gates_update(acc, c, hn);
        // FC2 incremental accumulation
#pragma unroll
        for (int e = 0; e < NU; ++e) {
            float hv = hn[e];
#pragma unroll
            for (int p = 0; p < Pn; ++p)
                yacc[p] = fmaf(w2[p * (Pn * Hn) + ps * Hn + j0 + e], hv, yacc[p]);
        }
        __syncthreads();   // all reads of h2 / g2s for this step done
        if (ps < Pn - 1) {
#pragma unroll
            for (int e = 0; e < NU; ++e) {
                int j = j0 + e;
                hbuf[((j >> 2) * ROWS + row) * 4 + (j & 3)] = hn[e];
            }
        }
        __syncthreads();
    }

    // ---- FC2 reduce across the 20 chunks + bias + sigmoid ----
    float* yp = g2s;   // alias: g2s no longer read
#pragma unroll
    for (int p = 0; p < Pn; ++p)
        yp[(hq * ROWS + row) * Pn + p] = yacc[p];
    __syncthreads();
    if (tid < ROWS * Pn) {
        int r = tid & 31;
        int p = tid >> 5;          // 0..6
        float s = b2[p];
#pragma unroll
        for (int q = 0; q < NTHREADS / 64 * 2; ++q)   // 20 chunks
            s += yp[(q * ROWS + r) * Pn + p];
        out[(blockIdx.x * ROWS + r) * Pn + p] = sigmoidf_(s);
    }
}

extern "C" void kernel_launch(void* const* d_in, const int* in_sizes, int n_in,
                              void* d_out, int out_size, void* d_ws, size_t ws_size,
                              hipStream_t stream) {
    const float* x    = (const float*)d_in[0];
    const float* W1   = (const float*)d_in[1];
    const float* b1   = (const float*)d_in[2];
    const float* Wih1 = (const float*)d_in[3];
    const float* Whh1 = (const float*)d_in[4];
    const float* bih1 = (const float*)d_in[5];
    const float* bhh1 = (const float*)d_in[6];
    const float* Wih2 = (const float*)d_in[7];
    const float* Whh2 = (const float*)d_in[8];
    const float* bih2 = (const float*)d_in[9];
    const float* bhh2 = (const float*)d_in[10];
    const float* W2   = (const float*)d_in[11];
    const float* b2   = (const float*)d_in[12];
    float* out = (float*)d_out;
    float* ws  = (float*)d_ws;

    precompute_kernel<<<2, 256, 0, stream>>>(W1, b1, Wih1, bih1, bhh1, ws);
    lstm_fused<<<NBLK, NTHREADS, 0, stream>>>(x, Whh1, Wih2, Whh2, bih2, bhh2,
                                              W2, b2, ws, out);
}

// Round 4
// 463.185 us; speedup vs baseline: 8.1447x; 6.4587x over previous
//
#include <hip/hip_runtime.h>
#include <math.h>

// Problem constants
#define Tn 30
#define Bn 16384
#define Hn 100
#define Pn 7

// MFMA tiling: N padded 400 -> 448 (each gate 100 -> 112 so unit j's 4 gates share a lane)
#define NTI 28            // n-tiles of 16
#define KTI 4             // k-tiles of 32 (K padded 100 -> 128 with zeros)
#define KP 136            // h row pitch in bf16 elems (272B = 17*16 -> 16B-aligned frag reads)
#define NFRAG (NTI * KTI) // 112 B-fragments per matrix
#define FRAG_BYTES (NFRAG * 64 * 16)   // 114688
#define HB_USHORT (16 * KP)            // per-wave h buffer (16 rows)
#define SMEM_BYTES (FRAG_BYTES + 4 * HB_USHORT * 2)   // 132096

// ws layout (bytes): [0,3200) u1/wc1 f32; frag arrays at 4096 + mat*FRAG_BYTES, mat=0:Whh1 1:Wih2 2:Whh2
#define WS_FRAG_OFF 4096

typedef __attribute__((ext_vector_type(8))) short short8;   // 8 bf16 (4 VGPRs)
typedef __attribute__((ext_vector_type(4))) float floatx4;  // MFMA C/D

__device__ __forceinline__ float sigmoidf_(float v) {
    return 1.0f / (1.0f + __expf(-v));
}
__device__ __forceinline__ float tanhf_(float v) {
    return 1.0f - 2.0f / (__expf(2.0f * v) + 1.0f);
}
__device__ __forceinline__ unsigned short f2bf(float v) {
    unsigned int u = __float_as_uint(v);
    unsigned int r = (u + 0x7FFFu + ((u >> 16) & 1u)) >> 16;   // RNE
    return (unsigned short)r;
}

// ws[0..399] = u1[j] = Wih1[j,:]·W1 (rank-1 FC1 fold); ws[400..799] = Wih1[j,:]·b1 + bih1[j] + bhh1[j]
__global__ void precompute_kernel(const float* __restrict__ W1,
                                  const float* __restrict__ b1,
                                  const float* __restrict__ Wih1,
                                  const float* __restrict__ bih1,
                                  const float* __restrict__ bhh1,
                                  float* __restrict__ ws) {
    int j = blockIdx.x * blockDim.x + threadIdx.x;
    if (j < 400) {
        float u = 0.f, w = 0.f;
        for (int k = 0; k < Hn; ++k) {
            float a = Wih1[j * Hn + k];
            u += a * W1[k];
            w += a * b1[k];
        }
        ws[j] = u;
        ws[400 + j] = w + bih1[j] + bhh1[j];
    }
}

// Pack the 3 recurrent-side matrices (400x100 f32, gate-major) into bf16 B-fragment layout.
// B[k][n]: n = lane&15, k = (lane>>4)*8 + j  (16x16x32 bf16 B-operand mapping).
// N-padded: n' = G*112 + r (r<100 real, else 0); K-padded: k<100 real, else 0.
__global__ void pack_kernel(const float* __restrict__ Whh1,
                            const float* __restrict__ Wih2,
                            const float* __restrict__ Whh2,
                            float* __restrict__ ws) {
    int gid = blockIdx.x * 256 + threadIdx.x;   // 3 * 7168 total
    int mat = gid / (NFRAG * 64);
    int t = gid % (NFRAG * 64);
    int f = t >> 6;            // fragment id = nt*4 + kt
    int lane = t & 63;
    int l = lane & 15, q = lane >> 4;
    int nt = f >> 2, kt = f & 3;
    int np = nt * 16 + l;
    int G = np / 112, rr = np % 112;
    const float* W = (mat == 0) ? Whh1 : (mat == 1) ? Wih2 : Whh2;
    const float* wrow = W + (G * 100 + rr) * Hn;
    int kbase = kt * 32 + q * 8;
    unsigned short hh[8];
#pragma unroll
    for (int j = 0; j < 8; ++j) {
        int k = kbase + j;
        float v = (rr < 100 && k < 100) ? wrow[k] : 0.f;
        hh[j] = f2bf(v);
    }
    uint4 u;
    u.x = (unsigned)hh[0] | ((unsigned)hh[1] << 16);
    u.y = (unsigned)hh[2] | ((unsigned)hh[3] << 16);
    u.z = (unsigned)hh[4] | ((unsigned)hh[5] << 16);
    u.w = (unsigned)hh[6] | ((unsigned)hh[7] << 16);
    uint4* dst = (uint4*)((char*)ws + WS_FRAG_OFF + mat * FRAG_BYTES);
    dst[f * 64 + lane] = u;
}

// Fully fused recurrent kernel. One wave owns 16 batch rows for the whole network:
// no per-step __syncthreads (h is wave-private LDS; barriers only around frag repacks).
__global__ __launch_bounds__(256, 1) void lstm_fused(
    const float* __restrict__ x,     // (T,B)
    const float* __restrict__ ws,    // u1/wc1 + packed frags
    const float* __restrict__ bih2,
    const float* __restrict__ bhh2,
    const float* __restrict__ w2,    // (7,700)
    const float* __restrict__ b2,    // (7,)
    float* __restrict__ out)         // (B,7)
{
    extern __shared__ char smem[];
    short8* wf = (short8*)smem;                           // 112 frags x 64 lanes x 16B
    unsigned short* hball = (unsigned short*)(smem + FRAG_BYTES);

    const int tid = threadIdx.x;
    const int wave = tid >> 6, lane = tid & 63;
    const int l = lane & 15, q = lane >> 4;
    unsigned short* hb = hball + wave * HB_USHORT;        // this wave's 16-row h (bf16)
    const int rowbase = blockIdx.x * 64 + wave * 16;

    // zero h (covers K-pad cols so pad k contributes 0)
    for (int i = lane; i < HB_USHORT; i += 64) hb[i] = 0;

    // stage Whh1 frags: global(prepacked) -> LDS, coalesced uint4 copy
    {
        const uint4* src = (const uint4*)((const char*)ws + WS_FRAG_OFF);
        uint4* dst = (uint4*)smem;
        for (int i = tid; i < FRAG_BYTES / 16; i += 256) dst[i] = src[i];
    }
    __syncthreads();

    // preload per-lane x-projection coefficients (n' = nt*16 + l -> gate G, unit j)
    const float* u1 = ws;
    const float* wc1 = ws + 400;
    float u1v[NTI], wc1v[NTI];
#pragma unroll
    for (int nt = 0; nt < NTI; ++nt) {
        int G = nt / 7, t7 = nt % 7;
        int j = t7 * 16 + l;
        u1v[nt] = (j < 100) ? u1[G * 100 + j] : 0.f;
        wc1v[nt] = (j < 100) ? wc1[G * 100 + j] : 0.f;
    }

    floatx4 cst[7];   // cell state: unit j = t7*16+l, rows m = 4q+r
#pragma unroll
    for (int t7 = 0; t7 < 7; ++t7) cst[t7] = (floatx4){0.f, 0.f, 0.f, 0.f};

    // ---- Phase 1: LSTM1, 30 steps, no barriers ----
    for (int t = 0; t < Tn; ++t) {
        float xv[4];
#pragma unroll
        for (int r = 0; r < 4; ++r) xv[r] = x[t * Bn + rowbase + 4 * q + r];
        short8 af[KTI];   // A[m=l][k = kt*32 + q*8 + j]
#pragma unroll
        for (int kt = 0; kt < KTI; ++kt)
            af[kt] = *(const short8*)(hb + l * KP + kt * 32 + q * 8);
        floatx4 acc[NTI];
#pragma unroll
        for (int nt = 0; nt < NTI; ++nt)
#pragma unroll
            for (int r = 0; r < 4; ++r)
                acc[nt][r] = fmaf(xv[r], u1v[nt], wc1v[nt]);
#pragma unroll
        for (int nt = 0; nt < NTI; ++nt)
#pragma unroll
            for (int kt = 0; kt < KTI; ++kt)
                acc[nt] = __builtin_amdgcn_mfma_f32_16x16x32_bf16(
                    af[kt], wf[(nt * 4 + kt) * 64 + lane], acc[nt], 0, 0, 0);
        // epilogue: gates -> c,h ; write h (bf16) back to wave-private LDS
#pragma unroll
        for (int t7 = 0; t7 < 7; ++t7) {
            int j = t7 * 16 + l;
#pragma unroll
            for (int r = 0; r < 4; ++r) {
                float iv = sigmoidf_(acc[t7][r]);
                float fv = sigmoidf_(acc[7 + t7][r]);
                float gv = tanhf_(acc[14 + t7][r]);
                float ov = sigmoidf_(acc[21 + t7][r]);
                float cc = fv * cst[t7][r] + iv * gv;
                cst[t7][r] = cc;
                hb[(4 * q + r) * KP + j] = f2bf(ov * tanhf_(cc));
            }
        }
    }
    __syncthreads();   // all waves done with Whh1 frags

    // stage Wih2 frags
    {
        const uint4* src = (const uint4*)((const char*)ws + WS_FRAG_OFF + FRAG_BYTES);
        uint4* dst = (uint4*)smem;
        for (int i = tid; i < FRAG_BYTES / 16; i += 256) dst[i] = src[i];
    }
    __syncthreads();

    // gin2 = (bih2 + bhh2) + last · Wih2^T  — computed once, held in registers
    floatx4 gin2[NTI];
    {
        short8 af[KTI];
#pragma unroll
        for (int kt = 0; kt < KTI; ++kt)
            af[kt] = *(const short8*)(hb + l * KP + kt * 32 + q * 8);
#pragma unroll
        for (int nt = 0; nt < NTI; ++nt) {
            int G = nt / 7, t7 = nt % 7;
            int j = t7 * 16 + l;
            float bv = (j < 100) ? (bih2[G * 100 + j] + bhh2[G * 100 + j]) : 0.f;
            gin2[nt] = (floatx4){bv, bv, bv, bv};
#pragma unroll
            for (int kt = 0; kt < KTI; ++kt)
                gin2[nt] = __builtin_amdgcn_mfma_f32_16x16x32_bf16(
                    af[kt], wf[(nt * 4 + kt) * 64 + lane], gin2[nt], 0, 0, 0);
        }
    }
    __syncthreads();   // done with Wih2 frags

    // stage Whh2 frags
    {
        const uint4* src = (const uint4*)((const char*)ws + WS_FRAG_OFF + 2 * FRAG_BYTES);
        uint4* dst = (uint4*)smem;
        for (int i = tid; i < FRAG_BYTES / 16; i += 256) dst[i] = src[i];
    }
    __syncthreads();

    // ---- Phase 2: LSTM2, 7 steps (input projection = gin2 const), FC2 accumulated ----
    floatx4 yacc[Pn];
#pragma unroll
    for (int p = 0; p < Pn; ++p) yacc[p] = (floatx4){0.f, 0.f, 0.f, 0.f};

    for (int ps = 0; ps < Pn; ++ps) {
        short8 af[KTI];
#pragma unroll
        for (int kt = 0; kt < KTI; ++kt)
            af[kt] = *(const short8*)(hb + l * KP + kt * 32 + q * 8);
        floatx4 acc[NTI];
#pragma unroll
        for (int nt = 0; nt < NTI; ++nt) acc[nt] = gin2[nt];
#pragma unroll
        for (int nt = 0; nt < NTI; ++nt)
#pragma unroll
            for (int kt = 0; kt < KTI; ++kt)
                acc[nt] = __builtin_amdgcn_mfma_f32_16x16x32_bf16(
                    af[kt], wf[(nt * 4 + kt) * 64 + lane], acc[nt], 0, 0, 0);
#pragma unroll
        for (int t7 = 0; t7 < 7; ++t7) {
            int j = t7 * 16 + l;
            float hv[4];
#pragma unroll
            for (int r = 0; r < 4; ++r) {
                float iv = sigmoidf_(acc[t7][r]);
                float fv = sigmoidf_(acc[7 + t7][r]);
                float gv = tanhf_(acc[14 + t7][r]);
                float ov = sigmoidf_(acc[21 + t7][r]);
                float cc = fv * cst[t7][r] + iv * gv;
                cst[t7][r] = cc;
                hv[r] = ov * tanhf_(cc);
                hb[(4 * q + r) * KP + j] = f2bf(hv[r]);
            }
            // FC2: y[p] += W2[p][ps*100 + j] * h2[j]
#pragma unroll
            for (int p = 0; p < Pn; ++p) {
                float wv = (j < 100) ? w2[p * (Pn * Hn) + ps * Hn + j] : 0.f;
#pragma unroll
                for (int r = 0; r < 4; ++r)
                    yacc[p][r] = fmaf(wv, hv[r], yacc[p][r]);
            }
        }
    }

    // ---- reduce FC2 partials across the 16 n-lanes (butterfly), bias + sigmoid, store ----
#pragma unroll
    for (int p = 0; p < Pn; ++p) {
        float bias = b2[p];
#pragma unroll
        for (int r = 0; r < 4; ++r) {
            float s = yacc[p][r];
            s += __shfl_xor(s, 1);
            s += __shfl_xor(s, 2);
            s += __shfl_xor(s, 4);
            s += __shfl_xor(s, 8);
            if (l == 0)
                out[(rowbase + 4 * q + r) * Pn + p] = sigmoidf_(s + bias);
        }
    }
}

extern "C" void kernel_launch(void* const* d_in, const int* in_sizes, int n_in,
                              void* d_out, int out_size, void* d_ws, size_t ws_size,
                              hipStream_t stream) {
    const float* x    = (const float*)d_in[0];
    const float* W1   = (const float*)d_in[1];
    const float* b1   = (const float*)d_in[2];
    const float* Wih1 = (const float*)d_in[3];
    const float* Whh1 = (const float*)d_in[4];
    const float* bih1 = (const float*)d_in[5];
    const float* bhh1 = (const float*)d_in[6];
    const float* Wih2 = (const float*)d_in[7];
    const float* Whh2 = (const float*)d_in[8];
    const float* bih2 = (const float*)d_in[9];
    const float* bhh2 = (const float*)d_in[10];
    const float* W2   = (const float*)d_in[11];
    const float* b2   = (const float*)d_in[12];
    float* out = (float*)d_out;
    float* ws  = (float*)d_ws;

    // allow >64KB dynamic LDS (132096B); idempotent, capture-safe
    (void)hipFuncSetAttribute((const void*)lstm_fused,
                              hipFuncAttributeMaxDynamicSharedMemorySize, SMEM_BYTES);

    precompute_kernel<<<2, 256, 0, stream>>>(W1, b1, Wih1, bih1, bhh1, ws);
    pack_kernel<<<(3 * NFRAG * 64) / 256, 256, 0, stream>>>(Whh1, Wih2, Whh2, ws);
    lstm_fused<<<Bn / 64, 256, SMEM_BYTES, stream>>>(x, ws, bih2, bhh2, W2, b2, out);
}

// Round 5
// 278.693 us; speedup vs baseline: 13.5365x; 1.6620x over previous
//
#include <hip/hip_runtime.h>
#include <math.h>

// Problem constants
#define Tn 30
#define Bn 16384
#define Hn 100
#define Pn 7

// Tiling: gates padded 100->128 units => N=512 (32 n-tiles of 16); K padded 100->128 (4 k-tiles of 32).
// 4 waves/block; wave w owns unit-blocks ag in {2w, 2w+1} (32 units, all 4 gates) for ALL 64 block rows.
// B-fragments (32 per wave, 16B/lane each) live in REGISTERS for the whole kernel.
#define KP 136            // h buffer row pitch (ushort elems); 272B -> 16B-aligned A-frag reads
#define RP 68             // gin2 row pitch (ushort elems); 136B stride -> ~2-way banks
#define NFRAG 128         // B-frags per matrix (32 nt x 4 kt)
#define FRAG_BYTES (NFRAG * 64 * 16)   // 131072 per matrix
#define WS_FRAG_OFF 4096
#define HBUF_USH (64 * KP)                       // one h buffer (64 rows), ushorts
#define SMEM_BYTES (2 * HBUF_USH * 2 + 512 * RP * 2)   // 34816 + 69632 = 104448

typedef __attribute__((ext_vector_type(8))) short short8;   // 8 bf16 (4 VGPRs)
typedef __attribute__((ext_vector_type(4))) float floatx4;  // MFMA C/D

__device__ __forceinline__ float rcp_(float v) { return __builtin_amdgcn_rcpf(v); }
__device__ __forceinline__ float sig_(float v) { return rcp_(1.0f + __expf(-v)); }
__device__ __forceinline__ float tanh_(float v) { return 1.0f - 2.0f * rcp_(__expf(2.0f * v) + 1.0f); }
__device__ __forceinline__ unsigned short f2bf(float v) {
    unsigned int u = __float_as_uint(v);
    return (unsigned short)((u + 0x7FFFu + ((u >> 16) & 1u)) >> 16);   // RNE
}

// ws[0..399] = u1[j] = Wih1[j,:]·W1 (rank-1 FC1 fold); ws[400..799] = Wih1[j,:]·b1 + bih1[j] + bhh1[j]
__global__ void precompute_kernel(const float* __restrict__ W1,
                                  const float* __restrict__ b1,
                                  const float* __restrict__ Wih1,
                                  const float* __restrict__ bih1,
                                  const float* __restrict__ bhh1,
                                  float* __restrict__ ws) {
    int j = blockIdx.x * blockDim.x + threadIdx.x;
    if (j < 400) {
        float u = 0.f, w = 0.f;
        for (int k = 0; k < Hn; ++k) {
            float a = Wih1[j * Hn + k];
            u += a * W1[k];
            w += a * b1[k];
        }
        ws[j] = u;
        ws[400 + j] = w + bih1[j] + bhh1[j];
    }
}

// Pack 3 recurrent matrices (400x100 f32) into bf16 B-frag layout, gates padded to 128 units.
// B[k][n]: n = lane&15, k = (lane>>4)*8 + jj (16x16x32 bf16 B mapping, HW-verified in R4).
__global__ void pack_kernel(const float* __restrict__ Whh1,
                            const float* __restrict__ Wih2,
                            const float* __restrict__ Whh2,
                            float* __restrict__ ws) {
    int gid = blockIdx.x * 256 + threadIdx.x;   // 3 * 128 * 64 = 24576
    int mat = gid / (NFRAG * 64);
    int t = gid % (NFRAG * 64);
    int f = t >> 6, lane = t & 63;
    int l = lane & 15, q = lane >> 4;
    int nt = f >> 2, kt = f & 3;
    int G = nt >> 3, ag = nt & 7;
    int j = ag * 16 + l;                         // unit within gate, 0..127 (real < 100)
    const float* W = (mat == 0) ? Whh1 : (mat == 1) ? Wih2 : Whh2;
    const float* wrow = W + (G * Hn + (j < Hn ? j : 0)) * Hn;
    int kbase = kt * 32 + q * 8;
    unsigned short hh[8];
#pragma unroll
    for (int jj = 0; jj < 8; ++jj) {
        int k = kbase + jj;
        hh[jj] = (j < Hn && k < Hn) ? f2bf(wrow[k]) : (unsigned short)0;
    }
    uint4 u;
    u.x = (unsigned)hh[0] | ((unsigned)hh[1] << 16);
    u.y = (unsigned)hh[2] | ((unsigned)hh[3] << 16);
    u.z = (unsigned)hh[4] | ((unsigned)hh[5] << 16);
    u.w = (unsigned)hh[6] | ((unsigned)hh[7] << 16);
    ((uint4*)((char*)ws + WS_FRAG_OFF + mat * FRAG_BYTES))[f * 64 + lane] = u;
}

__global__ __launch_bounds__(256, 1) void lstm_fused(
    const float* __restrict__ x,     // (T,B)
    const float* __restrict__ ws,    // u1/wc1 + packed frags
    const float* __restrict__ bih2,
    const float* __restrict__ bhh2,
    const float* __restrict__ w2,    // (7,700)
    const float* __restrict__ b2,    // (7,)
    float* __restrict__ out)         // (B,7)
{
    extern __shared__ unsigned short sm[];
    unsigned short* hb0 = sm;                   // h double buffer [row 64][k KP]
    unsigned short* hb1 = sm + HBUF_USH;
    unsigned short* g2 = sm + 2 * HBUF_USH;     // gin2 bf16 [n 512][row RP]

    const int tid = threadIdx.x;
    const int wave = tid >> 6, lane = tid & 63;
    const int l = lane & 15, q = lane >> 4;
    const int rowbase = blockIdx.x * 64;

    // zero both h buffers (covers K-pad; pad units stay exactly 0 through the recurrence)
    for (int i = tid; i < 2 * HBUF_USH; i += 256) sm[i] = 0;

    // ---- load this wave's 32 Whh1 B-frags into registers (held for all 30 steps) ----
    short8 bf[2][4][4];   // [al][G][kt]
    {
        const short8* fr = (const short8*)((const char*)ws + WS_FRAG_OFF);
#pragma unroll
        for (int al = 0; al < 2; ++al)
#pragma unroll
            for (int G = 0; G < 4; ++G)
#pragma unroll
                for (int kt = 0; kt < 4; ++kt)
                    bf[al][G][kt] = fr[((((G << 3) | (2 * wave + al)) << 2) + kt) * 64 + lane];
    }

    // per-lane x-projection coefficients
    float u1v[2][4], wc1v[2][4];
#pragma unroll
    for (int al = 0; al < 2; ++al)
#pragma unroll
        for (int G = 0; G < 4; ++G) {
            int j = (2 * wave + al) * 16 + l;
            u1v[al][G] = (j < Hn) ? ws[G * Hn + j] : 0.f;
            wc1v[al][G] = (j < Hn) ? ws[400 + G * Hn + j] : 0.f;
        }

    floatx4 cst[2][4];   // cell state [al][rg], rows 4q+r
#pragma unroll
    for (int al = 0; al < 2; ++al)
#pragma unroll
        for (int rg = 0; rg < 4; ++rg) cst[al][rg] = (floatx4){0.f, 0.f, 0.f, 0.f};

    __syncthreads();   // h buffers zeroed

    // x prefetch (t=0)
    float4 xc[4];
#pragma unroll
    for (int rg = 0; rg < 4; ++rg)
        xc[rg] = *(const float4*)(x + rowbase + rg * 16 + 4 * q);

    // ---- Phase 1: LSTM1, 30 steps, 1 barrier/step ----
    for (int t = 0; t < Tn; ++t) {
        unsigned short* hc = (t & 1) ? hb1 : hb0;
        unsigned short* hn = (t & 1) ? hb0 : hb1;
        float4 xn[4];
        int tn = (t < Tn - 1) ? t + 1 : t;
#pragma unroll
        for (int rg = 0; rg < 4; ++rg)
            xn[rg] = *(const float4*)(x + tn * Bn + rowbase + rg * 16 + 4 * q);
#pragma unroll
        for (int rg = 0; rg < 4; ++rg) {
            short8 af[4];   // A[m=l][k=kt*32+q*8+j], rows rg*16+m
#pragma unroll
            for (int kt = 0; kt < 4; ++kt)
                af[kt] = *(const short8*)(hc + (rg * 16 + l) * KP + kt * 32 + q * 8);
            floatx4 acc[2][4];
#pragma unroll
            for (int al = 0; al < 2; ++al)
#pragma unroll
                for (int G = 0; G < 4; ++G)
#pragma unroll
                    for (int r = 0; r < 4; ++r)
                        acc[al][G][r] = fmaf(xc[rg][r], u1v[al][G], wc1v[al][G]);
#pragma unroll
            for (int kt = 0; kt < 4; ++kt)
#pragma unroll
                for (int al = 0; al < 2; ++al)
#pragma unroll
                    for (int G = 0; G < 4; ++G)
                        acc[al][G] = __builtin_amdgcn_mfma_f32_16x16x32_bf16(
                            af[kt], bf[al][G][kt], acc[al][G], 0, 0, 0);
#pragma unroll
            for (int al = 0; al < 2; ++al) {
                int jcol = (2 * wave + al) * 16 + l;
#pragma unroll
                for (int r = 0; r < 4; ++r) {
                    float iv = sig_(acc[al][0][r]);
                    float fv = sig_(acc[al][1][r]);
                    float gv = tanh_(acc[al][2][r]);
                    float ov = sig_(acc[al][3][r]);
                    float cc = fv * cst[al][rg][r] + iv * gv;
                    cst[al][rg][r] = cc;
                    hn[(rg * 16 + 4 * q + r) * KP + jcol] = f2bf(ov * tanh_(cc));
                }
            }
        }
#pragma unroll
        for (int rg = 0; rg < 4; ++rg) xc[rg] = xn[rg];
        __syncthreads();
    }

    // ---- load Wih2 frags; gin2 = bias2 + last·Wih2^T, parked in LDS (bf16) ----
    {
        const short8* fr = (const short8*)((const char*)ws + WS_FRAG_OFF + FRAG_BYTES);
#pragma unroll
        for (int al = 0; al < 2; ++al)
#pragma unroll
            for (int G = 0; G < 4; ++G)
#pragma unroll
                for (int kt = 0; kt < 4; ++kt)
                    bf[al][G][kt] = fr[((((G << 3) | (2 * wave + al)) << 2) + kt) * 64 + lane];
    }
    {
        unsigned short* hl = hb0;   // last = h after t=29 (written to hb0)
        float bv[2][4];
#pragma unroll
        for (int al = 0; al < 2; ++al)
#pragma unroll
            for (int G = 0; G < 4; ++G) {
                int j = (2 * wave + al) * 16 + l;
                bv[al][G] = (j < Hn) ? (bih2[G * Hn + j] + bhh2[G * Hn + j]) : 0.f;
            }
#pragma unroll
        for (int rg = 0; rg < 4; ++rg) {
            short8 af[4];
#pragma unroll
            for (int kt = 0; kt < 4; ++kt)
                af[kt] = *(const short8*)(hl + (rg * 16 + l) * KP + kt * 32 + q * 8);
            floatx4 acc[2][4];
#pragma unroll
            for (int al = 0; al < 2; ++al)
#pragma unroll
                for (int G = 0; G < 4; ++G)
                    acc[al][G] = (floatx4){bv[al][G], bv[al][G], bv[al][G], bv[al][G]};
#pragma unroll
            for (int kt = 0; kt < 4; ++kt)
#pragma unroll
                for (int al = 0; al < 2; ++al)
#pragma unroll
                    for (int G = 0; G < 4; ++G)
                        acc[al][G] = __builtin_amdgcn_mfma_f32_16x16x32_bf16(
                            af[kt], bf[al][G][kt], acc[al][G], 0, 0, 0);
            // park as bf16 (wave-private n-range: no barrier needed)
#pragma unroll
            for (int al = 0; al < 2; ++al)
#pragma unroll
                for (int G = 0; G < 4; ++G) {
                    int n = G * 128 + (2 * wave + al) * 16 + l;
                    uint2 pk;
                    pk.x = (unsigned)f2bf(acc[al][G][0]) | ((unsigned)f2bf(acc[al][G][1]) << 16);
                    pk.y = (unsigned)f2bf(acc[al][G][2]) | ((unsigned)f2bf(acc[al][G][3]) << 16);
                    *(uint2*)(g2 + n * RP + rg * 16 + 4 * q) = pk;
                }
        }
    }
    // ---- load Whh2 frags (overwrite) ----
    {
        const short8* fr = (const short8*)((const char*)ws + WS_FRAG_OFF + 2 * FRAG_BYTES);
#pragma unroll
        for (int al = 0; al < 2; ++al)
#pragma unroll
            for (int G = 0; G < 4; ++G)
#pragma unroll
                for (int kt = 0; kt < 4; ++kt)
                    bf[al][G][kt] = fr[((((G << 3) | (2 * wave + al)) << 2) + kt) * 64 + lane];
    }

    // ---- Phase 2: LSTM2, 7 steps; FC2 accumulated incrementally ----
    floatx4 yacc[4][Pn];   // [rg][p], rows 4q+r
#pragma unroll
    for (int rg = 0; rg < 4; ++rg)
#pragma unroll
        for (int p = 0; p < Pn; ++p) yacc[rg][p] = (floatx4){0.f, 0.f, 0.f, 0.f};

    for (int ps = 0; ps < Pn; ++ps) {
        int t = Tn + ps;
        unsigned short* hc = (t & 1) ? hb1 : hb0;
        unsigned short* hn = (t & 1) ? hb0 : hb1;
        float w2v[2][Pn];
#pragma unroll
        for (int al = 0; al < 2; ++al) {
            int j = (2 * wave + al) * 16 + l;
#pragma unroll
            for (int p = 0; p < Pn; ++p)
                w2v[al][p] = (j < Hn) ? w2[p * (Pn * Hn) + ps * Hn + j] : 0.f;
        }
#pragma unroll
        for (int rg = 0; rg < 4; ++rg) {
            short8 af[4];
#pragma unroll
            for (int kt = 0; kt < 4; ++kt)
                af[kt] = *(const short8*)(hc + (rg * 16 + l) * KP + kt * 32 + q * 8);
            floatx4 acc[2][4];
#pragma unroll
            for (int al = 0; al < 2; ++al)
#pragma unroll
                for (int G = 0; G < 4; ++G) {
                    int n = G * 128 + (2 * wave + al) * 16 + l;
                    uint2 pk = *(const uint2*)(g2 + n * RP + rg * 16 + 4 * q);
                    acc[al][G][0] = __uint_as_float(pk.x << 16);
                    acc[al][G][1] = __uint_as_float(pk.x & 0xFFFF0000u);
                    acc[al][G][2] = __uint_as_float(pk.y << 16);
                    acc[al][G][3] = __uint_as_float(pk.y & 0xFFFF0000u);
                }
#pragma unroll
            for (int kt = 0; kt < 4; ++kt)
#pragma unroll
                for (int al = 0; al < 2; ++al)
#pragma unroll
                    for (int G = 0; G < 4; ++G)
                        acc[al][G] = __builtin_amdgcn_mfma_f32_16x16x32_bf16(
                            af[kt], bf[al][G][kt], acc[al][G], 0, 0, 0);
#pragma unroll
            for (int al = 0; al < 2; ++al) {
                int jcol = (2 * wave + al) * 16 + l;
#pragma unroll
                for (int r = 0; r < 4; ++r) {
                    float iv = sig_(acc[al][0][r]);
                    float fv = sig_(acc[al][1][r]);
                    float gv = tanh_(acc[al][2][r]);
                    float ov = sig_(acc[al][3][r]);
                    float cc = fv * cst[al][rg][r] + iv * gv;
                    cst[al][rg][r] = cc;
                    float hv = ov * tanh_(cc);
                    if (ps < Pn - 1)
                        hn[(rg * 16 + 4 * q + r) * KP + jcol] = f2bf(hv);
#pragma unroll
                    for (int p = 0; p < Pn; ++p)
                        yacc[rg][p][r] = fmaf(w2v[al][p], hv, yacc[rg][p][r]);
                }
            }
        }
        __syncthreads();
    }

    // ---- FC2 reduce: butterfly over the 16 unit-lanes, then cross-wave via LDS ----
    float* part = (float*)g2;   // alias: gin2 no longer read; [wave][row 64][p 7]
#pragma unroll
    for (int rg = 0; rg < 4; ++rg)
#pragma unroll
        for (int p = 0; p < Pn; ++p)
#pragma unroll
            for (int r = 0; r < 4; ++r) {
                float s = yacc[rg][p][r];
                s += __shfl_xor(s, 1);
                s += __shfl_xor(s, 2);
                s += __shfl_xor(s, 4);
                s += __shfl_xor(s, 8);
                if (l == 0)
                    part[(wave * 64 + rg * 16 + 4 * q + r) * Pn + p] = s;
            }
    __syncthreads();
    for (int i = tid; i < 64 * Pn; i += 256) {
        int row = i / Pn, p = i % Pn;
        float s = b2[p];
#pragma unroll
        for (int w = 0; w < 4; ++w) s += part[(w * 64 + row) * Pn + p];
        out[(rowbase + row) * Pn + p] = rcp_(1.0f + __expf(-s));
    }
}

extern "C" void kernel_launch(void* const* d_in, const int* in_sizes, int n_in,
                              void* d_out, int out_size, void* d_ws, size_t ws_size,
                              hipStream_t stream) {
    const float* x    = (const float*)d_in[0];
    const float* W1   = (const float*)d_in[1];
    const float* b1   = (const float*)d_in[2];
    const float* Wih1 = (const float*)d_in[3];
    const float* Whh1 = (const float*)d_in[4];
    const float* bih1 = (const float*)d_in[5];
    const float* bhh1 = (const float*)d_in[6];
    const float* Wih2 = (const float*)d_in[7];
    const float* Whh2 = (const float*)d_in[8];
    const float* bih2 = (const float*)d_in[9];
    const float* bhh2 = (const float*)d_in[10];
    const float* W2   = (const float*)d_in[11];
    const float* b2   = (const float*)d_in[12];
    float* out = (float*)d_out;
    float* ws  = (float*)d_ws;

    (void)hipFuncSetAttribute((const void*)lstm_fused,
                              hipFuncAttributeMaxDynamicSharedMemorySize, SMEM_BYTES);

    precompute_kernel<<<2, 256, 0, stream>>>(W1, b1, Wih1, bih1, bhh1, ws);
    pack_kernel<<<(3 * NFRAG * 64) / 256, 256, 0, stream>>>(Whh1, Wih2, Whh2, ws);
    lstm_fused<<<Bn / 64, 256, SMEM_BYTES, stream>>>(x, ws, bih2, bhh2, W2, b2, out);
}

// Round 6
// 218.551 us; speedup vs baseline: 17.2615x; 1.2752x over previous
//
#include <hip/hip_runtime.h>
#include <math.h>

// Problem constants
#define Tn 30
#define Bn 16384
#define Hn 100
#define Pn 7

// Tiling: gates padded 100->128 units => N=512 (32 n-tiles); K padded 100->128 (4 k-tiles of 32).
// 8 waves/block; wave w owns unit-block ag=w (16 units, all 4 gates) for ALL 64 block rows.
// B-fragments (16/wave) live in registers; h double-buffered in LDS; 1 barrier/step.
#define KP 136            // h row pitch (ushorts); 272B -> 16B-aligned A-frag reads
#define RP 68             // gin2 row pitch (ushorts)
#define NFRAG 128         // B-frags per matrix (32 nt x 4 kt)
#define FRAG_BYTES (NFRAG * 64 * 16)   // 131072 per matrix
#define WS_FRAG_OFF 4096
#define WS_W2_OFF (WS_FRAG_OFF + 3 * FRAG_BYTES)     // 28 W2 frags (7 ps x 4 kt)
#define HBUF_USH (64 * KP)
#define SMEM_BYTES (2 * HBUF_USH * 2 + 512 * RP * 2)   // 34816 + 69632 = 104448

typedef __attribute__((ext_vector_type(8))) short short8;   // 8 bf16 (4 VGPRs)
typedef __attribute__((ext_vector_type(4))) float floatx4;  // MFMA C/D

__device__ __forceinline__ float rcp_(float v) { return __builtin_amdgcn_rcpf(v); }
__device__ __forceinline__ float sig_(float v) { return rcp_(1.0f + __expf(-v)); }
__device__ __forceinline__ float tanh_(float v) { return 1.0f - 2.0f * rcp_(__expf(2.0f * v) + 1.0f); }
__device__ __forceinline__ unsigned short f2bf(float v) {
    unsigned int u = __float_as_uint(v);
    return (unsigned short)((u + 0x7FFFu + ((u >> 16) & 1u)) >> 16);   // RNE
}

// ws[0..399] = u1[j] = Wih1[j,:]·W1 (rank-1 FC1 fold); ws[400..799] = Wih1[j,:]·b1 + bih1[j] + bhh1[j]
__global__ void precompute_kernel(const float* __restrict__ W1,
                                  const float* __restrict__ b1,
                                  const float* __restrict__ Wih1,
                                  const float* __restrict__ bih1,
                                  const float* __restrict__ bhh1,
                                  float* __restrict__ ws) {
    int j = blockIdx.x * blockDim.x + threadIdx.x;
    if (j < 400) {
        float u = 0.f, w = 0.f;
        for (int k = 0; k < Hn; ++k) {
            float a = Wih1[j * Hn + k];
            u += a * W1[k];
            w += a * b1[k];
        }
        ws[j] = u;
        ws[400 + j] = w + bih1[j] + bhh1[j];
    }
}

// Pack the 3 recurrent matrices (400x100) into bf16 B-frag layout (gates padded to 128 units),
// plus W2 (7 x 700) into 7x4 B-frags with n = p (7 of 16 lanes real).
// B[k][n]: n = lane&15, k = (lane>>4)*8 + jj  (16x16x32 bf16 B mapping, HW-verified R4/R5).
__global__ void pack_kernel(const float* __restrict__ Whh1,
                            const float* __restrict__ Wih2,
                            const float* __restrict__ Whh2,
                            const float* __restrict__ W2,
                            float* __restrict__ ws) {
    int gid = blockIdx.x * 256 + threadIdx.x;   // 3*128*64 + 28*64 = 26368
    int lane = gid & 63;
    int l = lane & 15, q = lane >> 4;
    unsigned short hh[8];
    uint4 u;
    if (gid < 3 * NFRAG * 64) {
        int mat = gid / (NFRAG * 64);
        int f = (gid % (NFRAG * 64)) >> 6;
        int nt = f >> 2, kt = f & 3;
        int G = nt >> 3, ag = nt & 7;
        int j = ag * 16 + l;
        const float* W = (mat == 0) ? Whh1 : (mat == 1) ? Wih2 : Whh2;
        const float* wrow = W + (G * Hn + (j < Hn ? j : 0)) * Hn;
        int kbase = kt * 32 + q * 8;
#pragma unroll
        for (int jj = 0; jj < 8; ++jj) {
            int k = kbase + jj;
            hh[jj] = (j < Hn && k < Hn) ? f2bf(wrow[k]) : (unsigned short)0;
        }
        u.x = (unsigned)hh[0] | ((unsigned)hh[1] << 16);
        u.y = (unsigned)hh[2] | ((unsigned)hh[3] << 16);
        u.z = (unsigned)hh[4] | ((unsigned)hh[5] << 16);
        u.w = (unsigned)hh[6] | ((unsigned)hh[7] << 16);
        ((uint4*)((char*)ws + WS_FRAG_OFF + mat * FRAG_BYTES))[f * 64 + lane] = u;
    } else {
        int t = gid - 3 * NFRAG * 64;           // 0..1791
        int f = t >> 6;                         // 0..27 = ps*4 + kt
        int ps = f >> 2, kt = f & 3;
        int kbase = kt * 32 + q * 8;
#pragma unroll
        for (int jj = 0; jj < 8; ++jj) {
            int k = kbase + jj;
            hh[jj] = (l < Pn && k < Hn) ? f2bf(W2[l * (Pn * Hn) + ps * Hn + k])
                                        : (unsigned short)0;
        }
        u.x = (unsigned)hh[0] | ((unsigned)hh[1] << 16);
        u.y = (unsigned)hh[2] | ((unsigned)hh[3] << 16);
        u.z = (unsigned)hh[4] | ((unsigned)hh[5] << 16);
        u.w = (unsigned)hh[6] | ((unsigned)hh[7] << 16);
        ((uint4*)((char*)ws + WS_W2_OFF))[f * 64 + lane] = u;
    }
}

__global__ __launch_bounds__(512, 2) void lstm_fused(
    const float* __restrict__ x,     // (T,B)
    const float* __restrict__ ws,    // u1/wc1 + packed frags
    const float* __restrict__ bih2,
    const float* __restrict__ bhh2,
    const float* __restrict__ b2,    // (7,)
    float* __restrict__ out)         // (B,7)
{
    extern __shared__ unsigned short sm[];
    unsigned short* hb0 = sm;                   // h double buffer [row 64][k KP]
    unsigned short* hb1 = sm + HBUF_USH;
    unsigned short* g2 = sm + 2 * HBUF_USH;     // gin2 bf16 [n 512][row RP]

    const int tid = threadIdx.x;
    const int wave = tid >> 6, lane = tid & 63;
    const int l = lane & 15, q = lane >> 4;
    const int jcol = wave * 16 + l;             // this wave's unit column (0..127)
    const int rowbase = blockIdx.x * 64;

    for (int i = tid; i < 2 * HBUF_USH; i += 512) sm[i] = 0;

    // this wave's 16 Whh1 B-frags -> registers (held for all 30 steps)
    short8 bf[4][4];   // [G][kt]
    {
        const short8* fr = (const short8*)((const char*)ws + WS_FRAG_OFF);
#pragma unroll
        for (int G = 0; G < 4; ++G)
#pragma unroll
            for (int kt = 0; kt < 4; ++kt)
                bf[G][kt] = fr[((((G << 3) | wave) << 2) + kt) * 64 + lane];
    }
    float u1v[4], wc1v[4];
#pragma unroll
    for (int G = 0; G < 4; ++G) {
        u1v[G] = (jcol < Hn) ? ws[G * Hn + jcol] : 0.f;
        wc1v[G] = (jcol < Hn) ? ws[400 + G * Hn + jcol] : 0.f;
    }
    floatx4 cst[4];   // cell state per rg, rows 4q+r, unit jcol
#pragma unroll
    for (int rg = 0; rg < 4; ++rg) cst[rg] = (floatx4){0.f, 0.f, 0.f, 0.f};

    __syncthreads();   // h buffers zeroed

    float4 xc[4];
#pragma unroll
    for (int rg = 0; rg < 4; ++rg)
        xc[rg] = *(const float4*)(x + rowbase + rg * 16 + 4 * q);

    // ---- Phase 1: LSTM1, 30 steps, 1 barrier/step ----
    for (int t = 0; t < Tn; ++t) {
        unsigned short* hc = (t & 1) ? hb1 : hb0;
        unsigned short* hn = (t & 1) ? hb0 : hb1;
        int tn = (t < Tn - 1) ? t + 1 : t;
        float4 xn[4];
#pragma unroll
        for (int rg = 0; rg < 4; ++rg)
            xn[rg] = *(const float4*)(x + tn * Bn + rowbase + rg * 16 + 4 * q);
#pragma unroll
        for (int rg = 0; rg < 4; ++rg) {
            short8 af[4];   // A[m=l][k=kt*32+q*8+j], rows rg*16+m
#pragma unroll
            for (int kt = 0; kt < 4; ++kt)
                af[kt] = *(const short8*)(hc + (rg * 16 + l) * KP + kt * 32 + q * 8);
            floatx4 acc[4];
#pragma unroll
            for (int G = 0; G < 4; ++G)
#pragma unroll
                for (int r = 0; r < 4; ++r)
                    acc[G][r] = fmaf(xc[rg][r], u1v[G], wc1v[G]);
#pragma unroll
            for (int kt = 0; kt < 4; ++kt)
#pragma unroll
                for (int G = 0; G < 4; ++G)
                    acc[G] = __builtin_amdgcn_mfma_f32_16x16x32_bf16(
                        af[kt], bf[G][kt], acc[G], 0, 0, 0);
#pragma unroll
            for (int r = 0; r < 4; ++r) {
                float iv = sig_(acc[0][r]);
                float fv = sig_(acc[1][r]);
                float gv = tanh_(acc[2][r]);
                float ov = sig_(acc[3][r]);
                float cc = fv * cst[rg][r] + iv * gv;
                cst[rg][r] = cc;
                hn[(rg * 16 + 4 * q + r) * KP + jcol] = f2bf(ov * tanh_(cc));
            }
        }
#pragma unroll
        for (int rg = 0; rg < 4; ++rg) xc[rg] = xn[rg];
        __syncthreads();
    }

    // ---- Wih2 frags; gin2 = bias2 + last·Wih2^T parked in LDS (bf16, wave-private n) ----
    {
        const short8* fr = (const short8*)((const char*)ws + WS_FRAG_OFF + FRAG_BYTES);
#pragma unroll
        for (int G = 0; G < 4; ++G)
#pragma unroll
            for (int kt = 0; kt < 4; ++kt)
                bf[G][kt] = fr[((((G << 3) | wave) << 2) + kt) * 64 + lane];
    }
    {
        unsigned short* hl = hb0;   // last = h after t=29
        float bv[4];
#pragma unroll
        for (int G = 0; G < 4; ++G)
            bv[G] = (jcol < Hn) ? (bih2[G * Hn + jcol] + bhh2[G * Hn + jcol]) : 0.f;
#pragma unroll
        for (int rg = 0; rg < 4; ++rg) {
            short8 af[4];
#pragma unroll
            for (int kt = 0; kt < 4; ++kt)
                af[kt] = *(const short8*)(hl + (rg * 16 + l) * KP + kt * 32 + q * 8);
            floatx4 acc[4];
#pragma unroll
            for (int G = 0; G < 4; ++G)
                acc[G] = (floatx4){bv[G], bv[G], bv[G], bv[G]};
#pragma unroll
            for (int kt = 0; kt < 4; ++kt)
#pragma unroll
                for (int G = 0; G < 4; ++G)
                    acc[G] = __builtin_amdgcn_mfma_f32_16x16x32_bf16(
                        af[kt], bf[G][kt], acc[G], 0, 0, 0);
#pragma unroll
            for (int G = 0; G < 4; ++G) {
                int n = G * 128 + jcol;
                uint2 pk;
                pk.x = (unsigned)f2bf(acc[G][0]) | ((unsigned)f2bf(acc[G][1]) << 16);
                pk.y = (unsigned)f2bf(acc[G][2]) | ((unsigned)f2bf(acc[G][3]) << 16);
                *(uint2*)(g2 + n * RP + rg * 16 + 4 * q) = pk;
            }
        }
    }
    // ---- Whh2 frags ----
    {
        const short8* fr = (const short8*)((const char*)ws + WS_FRAG_OFF + 2 * FRAG_BYTES);
#pragma unroll
        for (int G = 0; G < 4; ++G)
#pragma unroll
            for (int kt = 0; kt < 4; ++kt)
                bf[G][kt] = fr[((((G << 3) | wave) << 2) + kt) * 64 + lane];
    }

    // ---- Phase 2: LSTM2, 7 steps; FC2 via MFMA on waves 0-3 (wave w -> rg w, p = lane&15) ----
    const short8* w2fr = (const short8*)((const char*)ws + WS_W2_OFF);
    floatx4 yfc = (floatx4){0.f, 0.f, 0.f, 0.f};

    for (int ps = 0; ps < Pn; ++ps) {
        int t = Tn + ps;
        unsigned short* hc = (t & 1) ? hb1 : hb0;
        unsigned short* hn = (t & 1) ? hb0 : hb1;
        const bool dofc = (wave < 4) && (ps >= 1);   // hc holds h2 of step ps-1
        short8 w2f[4];
        if (dofc) {
#pragma unroll
            for (int kt = 0; kt < 4; ++kt)
                w2f[kt] = w2fr[((ps - 1) * 4 + kt) * 64 + lane];
        }
#pragma unroll
        for (int rg = 0; rg < 4; ++rg) {
            short8 af[4];
#pragma unroll
            for (int kt = 0; kt < 4; ++kt)
                af[kt] = *(const short8*)(hc + (rg * 16 + l) * KP + kt * 32 + q * 8);
            if (dofc && rg == wave) {
#pragma unroll
                for (int kt = 0; kt < 4; ++kt)
                    yfc = __builtin_amdgcn_mfma_f32_16x16x32_bf16(af[kt], w2f[kt], yfc, 0, 0, 0);
            }
            floatx4 acc[4];
#pragma unroll
            for (int G = 0; G < 4; ++G) {
                int n = G * 128 + jcol;
                uint2 pk = *(const uint2*)(g2 + n * RP + rg * 16 + 4 * q);
                acc[G][0] = __uint_as_float(pk.x << 16);
                acc[G][1] = __uint_as_float(pk.x & 0xFFFF0000u);
                acc[G][2] = __uint_as_float(pk.y << 16);
                acc[G][3] = __uint_as_float(pk.y & 0xFFFF0000u);
            }
#pragma unroll
            for (int kt = 0; kt < 4; ++kt)
#pragma unroll
                for (int G = 0; G < 4; ++G)
                    acc[G] = __builtin_amdgcn_mfma_f32_16x16x32_bf16(
                        af[kt], bf[G][kt], acc[G], 0, 0, 0);
#pragma unroll
            for (int r = 0; r < 4; ++r) {
                float iv = sig_(acc[0][r]);
                float fv = sig_(acc[1][r]);
                float gv = tanh_(acc[2][r]);
                float ov = sig_(acc[3][r]);
                float cc = fv * cst[rg][r] + iv * gv;
                cst[rg][r] = cc;
                hn[(rg * 16 + 4 * q + r) * KP + jcol] = f2bf(ov * tanh_(cc));   // ps=6 too (final FC2)
            }
        }
        __syncthreads();
    }

    // ---- final FC2 for h2 of ps=6 (in hb1: t=36 even -> hn=hb1), then bias+sigmoid+store ----
    if (wave < 4) {
        short8 w2f[4], af[4];
#pragma unroll
        for (int kt = 0; kt < 4; ++kt) {
            w2f[kt] = w2fr[(6 * 4 + kt) * 64 + lane];
            af[kt] = *(const short8*)(hb1 + (wave * 16 + l) * KP + kt * 32 + q * 8);
        }
#pragma unroll
        for (int kt = 0; kt < 4; ++kt)
            yfc = __builtin_amdgcn_mfma_f32_16x16x32_bf16(af[kt], w2f[kt], yfc, 0, 0, 0);
        if (l < Pn) {
            float bias = b2[l];
#pragma unroll
            for (int r = 0; r < 4; ++r)
                out[(rowbase + wave * 16 + 4 * q + r) * Pn + l] = sig_(yfc[r] + bias);
        }
    }
}

extern "C" void kernel_launch(void* const* d_in, const int* in_sizes, int n_in,
                              void* d_out, int out_size, void* d_ws, size_t ws_size,
                              hipStream_t stream) {
    const float* x    = (const float*)d_in[0];
    const float* W1   = (const float*)d_in[1];
    const float* b1   = (const float*)d_in[2];
    const float* Wih1 = (const float*)d_in[3];
    const float* Whh1 = (const float*)d_in[4];
    const float* bih1 = (const float*)d_in[5];
    const float* bhh1 = (const float*)d_in[6];
    const float* Wih2 = (const float*)d_in[7];
    const float* Whh2 = (const float*)d_in[8];
    const float* bih2 = (const float*)d_in[9];
    const float* bhh2 = (const float*)d_in[10];
    const float* W2   = (const float*)d_in[11];
    const float* b2   = (const float*)d_in[12];
    float* out = (float*)d_out;
    float* ws  = (float*)d_ws;

    (void)hipFuncSetAttribute((const void*)lstm_fused,
                              hipFuncAttributeMaxDynamicSharedMemorySize, SMEM_BYTES);

    precompute_kernel<<<2, 256, 0, stream>>>(W1, b1, Wih1, bih1, bhh1, ws);
    pack_kernel<<<(3 * NFRAG * 64 + 28 * 64) / 256, 256, 0, stream>>>(Whh1, Wih2, Whh2, W2, ws);
    lstm_fused<<<Bn / 64, 512, SMEM_BYTES, stream>>>(x, ws, bih2, bhh2, b2, out);
}